// Round 6
// baseline (491.077 us; speedup 1.0000x reference)
//
#include <hip/hip_runtime.h>

#define NN 100000
#define EE 1600000
#define GG 1000
#define PERG 100
#define KK 30
#define HH 64

#define NB 782      // buckets of 128 nodes: 782*128 = 100096 >= NN
#define CAP 4096    // max edges/bucket (mean 2048, sigma ~45 -> huge margin)
#define CHB 4096    // edges per bucket_kernel block -> 391 blocks (~6 waves/CU)

__global__ __launch_bounds__(1024) void zero_int(int* p, int n) {
  int i = blockIdx.x * 1024 + threadIdx.x;
  if (i < n) p[i] = 0;
}

// Phase B: bucket edges by dst>>7 with LDS histograms + per-(block,bucket) run
// reservation.
__global__ __launch_bounds__(256) void bucket_kernel(const int* __restrict__ src,
                                                     const int* __restrict__ dst,
                                                     int* __restrict__ gcur,
                                                     int* __restrict__ pairs) {
  __shared__ int lhist[NB];
  __shared__ int lbase[NB];
  __shared__ int lcur[NB];
  const int t = threadIdx.x;
  const int c0 = blockIdx.x * CHB;
  const int c1 = min(c0 + CHB, EE);
  for (int b = t; b < NB; b += 256) {
    lhist[b] = 0;
    lcur[b] = 0;
  }
  __syncthreads();
  for (int e = c0 + t; e < c1; e += 256) atomicAdd(&lhist[dst[e] >> 7], 1);
  __syncthreads();
  for (int b = t; b < NB; b += 256) {
    int c = lhist[b];
    lbase[b] = c ? atomicAdd(&gcur[b], c) : 0;
  }
  __syncthreads();
  for (int e = c0 + t; e < c1; e += 256) {
    int d = dst[e];
    int b = d >> 7;
    int p = atomicAdd(&lcur[b], 1);
    pairs[b * CAP + lbase[b] + p] = (src[e] << 7) | (d & 127);
  }
}

// exclusive scan of 782 bucket counts -> global CSR base per bucket
__global__ __launch_bounds__(1024) void bucket_scan(const int* __restrict__ gcur,
                                                    int* __restrict__ bbase) {
  __shared__ int tmp[1024];
  const int t = threadIdx.x;
  int v = (t < NB) ? gcur[t] : 0;
  tmp[t] = v;
  __syncthreads();
  for (int off = 1; off < 1024; off <<= 1) {
    int u = (t >= off) ? tmp[t - off] : 0;
    __syncthreads();
    tmp[t] += u;
    __syncthreads();
  }
  if (t < NB) bbase[t] = tmp[t] - v;
}

// Phase C: one block per bucket; 128-bin LDS counting sort -> row_start/cnt/eidx.
__global__ __launch_bounds__(256) void csr_kernel(const int* __restrict__ gcur,
                                                  const int* __restrict__ bbase,
                                                  const int* __restrict__ pairs,
                                                  int* __restrict__ row_start,
                                                  int* __restrict__ cnt,
                                                  int* __restrict__ eidx) {
  __shared__ int vals[CAP];
  __shared__ int hist[128];
  __shared__ int offs[128];
  __shared__ int cur[128];
  const int b = blockIdx.x;
  const int t = threadIdx.x;
  const int nb = gcur[b];
  const int base = bbase[b];
  if (t < 128) {
    hist[t] = 0;
    cur[t] = 0;
  }
  __syncthreads();
  for (int i = t; i < nb; i += 256) {
    int v = pairs[b * CAP + i];
    vals[i] = v;
    atomicAdd(&hist[v & 127], 1);
  }
  __syncthreads();
  if (t < 128) {
    int s = 0;
    for (int m = 0; m < t; ++m) s += hist[m];
    offs[t] = s;
    int node = b * 128 + t;
    if (node < NN) {
      row_start[node] = base + s;
      cnt[node] = hist[t];
    }
  }
  __syncthreads();
  for (int i = t; i < nb; i += 256) {
    int v = vals[i];
    int ld = v & 127;
    int p = atomicAdd(&cur[ld], 1);
    eidx[base + offs[ld] + p] = v >> 7;
  }
}

// X [NN,K] @ (WL[K,64] | WR[K,64]) -> P [NN,64], R [NN,64]
// BM=128, 8x8 register tile per thread. xs kept in [row][k-chunk] layout
// (width 40 words): staging = b128 writes with <=2-way banks (no transpose
// conflicts); A-fragments read as float4 along k (broadcast, conflict-free).
// 1.0 B LDS / FMA (was 1.5).
template <int K>
__global__ __launch_bounds__(256) void proj_kernel(const float* __restrict__ X,
                                                   const float* __restrict__ WL,
                                                   const float* __restrict__ WR,
                                                   float* __restrict__ P,
                                                   float* __restrict__ R) {
  constexpr int BM = 128, BK = 32, XSP = 40, WSP = 144;
  __shared__ float xs[BM * XSP];  // 20.5 KB
  __shared__ float ws[BK * WSP];  // 18.4 KB
  const int t = threadIdx.x;
  const int row0 = blockIdx.x * BM;
  const int tc = t & 15, tr = t >> 4;
  const int wcol = tc * 8 + (tc >> 2) * 4;  // swizzled W column (<=2-way banks)

  float acc[8][8];
#pragma unroll
  for (int i = 0; i < 8; ++i)
#pragma unroll
    for (int j = 0; j < 8; ++j) acc[i][j] = 0.f;

  for (int k0 = 0; k0 < K; k0 += BK) {
    __syncthreads();
    // stage X chunk: rows 0..127, k-slice of 32. Coalesced global f4 reads
    // (8 lanes cover one row's 128B), b128 LDS writes, bank=(8r+4c)%32 -> 2-way.
    for (int idx = t; idx < BM * 8; idx += 256) {
      int r = idx >> 3, c = idx & 7;
      int row = row0 + r;
      float4 v = make_float4(0.f, 0.f, 0.f, 0.f);
      if (row < NN) v = *reinterpret_cast<const float4*>(&X[(size_t)row * K + k0 + c * 4]);
      *reinterpret_cast<float4*>(&xs[r * XSP + c * 4]) = v;
    }
    // stage W chunk (both WL and WR) with swizzle
    for (int idx = t; idx < BK * 16; idx += 256) {
      int kr = idx >> 4, c4 = idx & 15;
      int gcl = c4 >> 1;
      int off = gcl * 8 + (gcl >> 2) * 4 + (c4 & 1) * 4;
      *reinterpret_cast<float4*>(&ws[kr * WSP + off]) =
          *reinterpret_cast<const float4*>(&WL[(k0 + kr) * 64 + c4 * 4]);
      int g2 = gcl + 8;
      int off2 = g2 * 8 + (g2 >> 2) * 4 + (c4 & 1) * 4;
      *reinterpret_cast<float4*>(&ws[kr * WSP + off2]) =
          *reinterpret_cast<const float4*>(&WR[(k0 + kr) * 64 + c4 * 4]);
    }
    __syncthreads();
    for (int kk4 = 0; kk4 < BK; kk4 += 4) {
      float4 a[8];
#pragma unroll
      for (int i = 0; i < 8; ++i)
        a[i] = *reinterpret_cast<const float4*>(&xs[(tr + 16 * i) * XSP + kk4]);
#pragma unroll
      for (int kk = 0; kk < 4; ++kk) {
        float4 b0 = *reinterpret_cast<const float4*>(&ws[(kk4 + kk) * WSP + wcol]);
        float4 b1 = *reinterpret_cast<const float4*>(&ws[(kk4 + kk) * WSP + wcol + 4]);
        float bv[8] = {b0.x, b0.y, b0.z, b0.w, b1.x, b1.y, b1.z, b1.w};
#pragma unroll
        for (int i = 0; i < 8; ++i) {
          float av = (kk == 0) ? a[i].x : (kk == 1) ? a[i].y : (kk == 2) ? a[i].z : a[i].w;
#pragma unroll
          for (int j = 0; j < 8; ++j) acc[i][j] = fmaf(av, bv[j], acc[i][j]);
        }
      }
    }
  }

  float* OUT = (tc < 8) ? P : R;
  int cb = (tc & 7) * 8;
#pragma unroll
  for (int i = 0; i < 8; ++i) {
    int row = row0 + tr + 16 * i;
    if (row < NN) {
      *reinterpret_cast<float4*>(&OUT[(size_t)row * 64 + cb]) =
          make_float4(acc[i][0], acc[i][1], acc[i][2], acc[i][3]);
      *reinterpret_cast<float4*>(&OUT[(size_t)row * 64 + cb + 4]) =
          make_float4(acc[i][4], acc[i][5], acc[i][6], acc[i][7]);
    }
  }
}

// one wave per node, quarter-wave per edge: 16 lanes x float4 = one 256B P row
// per quarter -> one dwordx4 instruction covers 4 edges; 16 edges in flight.
__global__ __launch_bounds__(256) void agg_kernel(const float* __restrict__ P,
                                                  const float* __restrict__ R,
                                                  const float* __restrict__ bias,
                                                  const int* __restrict__ row_start,
                                                  const int* __restrict__ cnt,
                                                  const int* __restrict__ eidx,
                                                  float* __restrict__ h,
                                                  float* __restrict__ keys) {
  int wid = (blockIdx.x * 256 + threadIdx.x) >> 6;
  int lane = threadIdx.x & 63;
  if (wid >= NN) return;
  const int q = lane >> 4;   // quarter 0..3
  const int ql = lane & 15;  // lane within quarter -> features [ql*4, ql*4+4)
  const int base = row_start[wid];
  const int deg = cnt[wid];
  float4 a0 = make_float4(0.f, 0.f, 0.f, 0.f);
  float4 a1 = make_float4(0.f, 0.f, 0.f, 0.f);

  for (int e0 = 0; e0 < deg; e0 += 64) {
    const int m = min(64, deg - e0);
    int idx = (lane < m) ? eidx[base + e0 + lane] : 0;
    for (int j = 0; j < m; j += 16) {
      const int eA = j + q, eB = j + 4 + q, eC = j + 8 + q, eD = j + 12 + q;
      const int sA = __shfl(idx, min(eA, m - 1));
      const int sB = __shfl(idx, min(eB, m - 1));
      const int sC = __shfl(idx, min(eC, m - 1));
      const int sD = __shfl(idx, min(eD, m - 1));
      const float wA = (eA < m) ? 1.f : 0.f;
      const float wB = (eB < m) ? 1.f : 0.f;
      const float wC = (eC < m) ? 1.f : 0.f;
      const float wD = (eD < m) ? 1.f : 0.f;
      float4 vA = *reinterpret_cast<const float4*>(&P[(size_t)sA * 64 + ql * 4]);
      float4 vB = *reinterpret_cast<const float4*>(&P[(size_t)sB * 64 + ql * 4]);
      float4 vC = *reinterpret_cast<const float4*>(&P[(size_t)sC * 64 + ql * 4]);
      float4 vD = *reinterpret_cast<const float4*>(&P[(size_t)sD * 64 + ql * 4]);
      a0.x = fmaf(wA, vA.x, a0.x); a0.y = fmaf(wA, vA.y, a0.y);
      a0.z = fmaf(wA, vA.z, a0.z); a0.w = fmaf(wA, vA.w, a0.w);
      a1.x = fmaf(wB, vB.x, a1.x); a1.y = fmaf(wB, vB.y, a1.y);
      a1.z = fmaf(wB, vB.z, a1.z); a1.w = fmaf(wB, vB.w, a1.w);
      a0.x = fmaf(wC, vC.x, a0.x); a0.y = fmaf(wC, vC.y, a0.y);
      a0.z = fmaf(wC, vC.z, a0.z); a0.w = fmaf(wC, vC.w, a0.w);
      a1.x = fmaf(wD, vD.x, a1.x); a1.y = fmaf(wD, vD.y, a1.y);
      a1.z = fmaf(wD, vD.z, a1.z); a1.w = fmaf(wD, vD.w, a1.w);
    }
  }

  float4 acc = make_float4(a0.x + a1.x, a0.y + a1.y, a0.z + a1.z, a0.w + a1.w);
#pragma unroll
  for (int d = 16; d < 64; d <<= 1) {
    acc.x += __shfl_xor(acc.x, d);
    acc.y += __shfl_xor(acc.y, d);
    acc.z += __shfl_xor(acc.z, d);
    acc.w += __shfl_xor(acc.w, d);
  }

  if (q == 0) {
    const float dv = fmaxf((float)deg, 1.0f);
    float4 r4 = *reinterpret_cast<const float4*>(&R[(size_t)wid * 64 + ql * 4]);
    float4 b4 = *reinterpret_cast<const float4*>(&bias[ql * 4]);
    float4 o;
    o.x = fmaxf(acc.x / dv + b4.x + r4.x, 0.f);
    o.y = fmaxf(acc.y / dv + b4.y + r4.y, 0.f);
    o.z = fmaxf(acc.z / dv + b4.z + r4.z, 0.f);
    o.w = fmaxf(acc.w / dv + b4.w + r4.w, 0.f);
    *reinterpret_cast<float4*>(&h[(size_t)wid * 64 + ql * 4]) = o;
    if (keys != nullptr && ql == 15) keys[wid] = o.w;  // feature 63
  }
}

// one block (256 thr) per graph: stable top-30, conv1d (conflict-free weights),
// MLP head. Keys come from the compact keys[] array (coalesced).
__global__ __launch_bounds__(256) void head_kernel(const float* __restrict__ h,
                                                   const float* __restrict__ keysArr,
                                                   const float* __restrict__ cw,
                                                   const float* __restrict__ cb,
                                                   const float* __restrict__ w1,
                                                   const float* __restrict__ bb1,
                                                   const float* __restrict__ w2,
                                                   const float* __restrict__ bb2,
                                                   float* __restrict__ out) {
  __shared__ float key[PERG];
  __shared__ int sel[KK];
  __shared__ float feat[34 * 65];   // rows 30..33 garbage-read only by dead lanes
  __shared__ float cwT[192 * 33];   // [k][o] padded: conflict-free stage + read
  __shared__ float z[896];          // conv output, flat q = o*28+p
  __shared__ float psum[256];
  const int g = blockIdx.x;
  const int t = threadIdx.x;

  for (int idx = t; idx < 32 * 192; idx += 256) {
    int o = idx / 192, k = idx % 192;
    cwT[k * 33 + o] = cw[idx];
  }
  if (t < PERG) key[t] = keysArr[g * PERG + t];
  __syncthreads();

  if (t < PERG) {
    float kv = key[t];
    int r = 0;
    for (int m = 0; m < PERG; ++m) {
      float km = key[m];
      r += (int)((km > kv) || (km == kv && m < t));
    }
    if (r < KK) sel[r] = t;
  }
  __syncthreads();

  for (int idx = t; idx < KK * HH; idx += 256) {
    int r = idx >> 6, f = idx & 63;
    feat[r * 65 + f] = h[(size_t)(g * PERG + sel[r]) * HH + f];
  }
  __syncthreads();

  {
    const int o = t & 31;
    const int pg = t >> 5;  // 0..7
    float zacc[4] = {0.f, 0.f, 0.f, 0.f};
    int i = 0, tt = 0;
    for (int k = 0; k < 192; ++k) {
      float c = cwT[k * 33 + o];
#pragma unroll
      for (int j = 0; j < 4; ++j) {
        int p = pg + 8 * j;
        zacc[j] = fmaf(c, feat[(p + tt) * 65 + i], zacc[j]);
      }
      if (++tt == 3) {
        tt = 0;
        ++i;
      }
    }
    float cbo = cb[o];
#pragma unroll
    for (int j = 0; j < 4; ++j) {
      int p = pg + 8 * j;
      if (p < 28) z[o * 28 + p] = fmaxf(zacc[j] + cbo, 0.f);
    }
  }
  __syncthreads();

  {
    const int hh = t & 63;
    const int quarter = t >> 6;
    const int q0 = quarter * 224;
    float acc = 0.f;
    for (int q = 0; q < 224; ++q)
      acc = fmaf(z[q0 + q], w1[(size_t)(q0 + q) * 64 + hh], acc);
    psum[t] = acc;
  }
  __syncthreads();

  if (t < 64) {
    float o1 = fmaxf(bb1[t] + psum[t] + psum[t + 64] + psum[t + 128] + psum[t + 192], 0.f);
    float v = o1 * w2[t];
#pragma unroll
    for (int off = 32; off > 0; off >>= 1) v += __shfl_down(v, off);
    if (t == 0) out[g] = v + bb2[0];
  }
}

extern "C" void kernel_launch(void* const* d_in, const int* in_sizes, int n_in,
                              void* d_out, int out_size, void* d_ws, size_t ws_size,
                              hipStream_t stream) {
  const float* x = (const float*)d_in[0];
  const int* src = (const int*)d_in[1];
  const int* dst = (const int*)d_in[2];
  const float* wl1 = (const float*)d_in[4];
  const float* wr1 = (const float*)d_in[5];
  const float* b1 = (const float*)d_in[6];
  const float* wl2 = (const float*)d_in[7];
  const float* wr2 = (const float*)d_in[8];
  const float* b2 = (const float*)d_in[9];
  const float* wl3 = (const float*)d_in[10];
  const float* wr3 = (const float*)d_in[11];
  const float* b3 = (const float*)d_in[12];
  const float* cw = (const float*)d_in[13];
  const float* cb = (const float*)d_in[14];
  const float* w1 = (const float*)d_in[15];
  const float* bb1 = (const float*)d_in[16];
  const float* w2 = (const float*)d_in[17];
  const float* bb2 = (const float*)d_in[18];
  float* out = (float*)d_out;

  char* w = (char*)d_ws;
  auto carve = [&](size_t bytes) {
    char* p = w;
    w += (bytes + 255) & ~(size_t)255;
    return p;
  };
  int* row_start = (int*)carve((size_t)NN * 4);
  int* cnt = (int*)carve((size_t)NN * 4);
  int* eidx = (int*)carve((size_t)EE * 4);
  float* P = (float*)carve((size_t)NN * 64 * 4);
  float* R = (float*)carve((size_t)NN * 64 * 4);
  float* hbuf = (float*)carve((size_t)NN * 64 * 4);
  float* keys = (float*)carve((size_t)NN * 4);
  int* gcur = (int*)carve((size_t)NB * 4);
  int* bbase = (int*)carve((size_t)NB * 4);
  int* pairs = (int*)P;  // aliases P (csr finishes before proj1 writes P)

  zero_int<<<1, 1024, 0, stream>>>(gcur, NB);
  bucket_kernel<<<(EE + CHB - 1) / CHB, 256, 0, stream>>>(src, dst, gcur, pairs);
  bucket_scan<<<1, 1024, 0, stream>>>(gcur, bbase);
  csr_kernel<<<NB, 256, 0, stream>>>(gcur, bbase, pairs, row_start, cnt, eidx);

  const int projGrid = (NN + 127) / 128;
  const int aggGrid = (NN + 3) / 4;
  proj_kernel<128><<<projGrid, 256, 0, stream>>>(x, wl1, wr1, P, R);
  agg_kernel<<<aggGrid, 256, 0, stream>>>(P, R, b1, row_start, cnt, eidx, hbuf, nullptr);
  proj_kernel<64><<<projGrid, 256, 0, stream>>>(hbuf, wl2, wr2, P, R);
  agg_kernel<<<aggGrid, 256, 0, stream>>>(P, R, b2, row_start, cnt, eidx, hbuf, nullptr);
  proj_kernel<64><<<projGrid, 256, 0, stream>>>(hbuf, wl3, wr3, P, R);
  agg_kernel<<<aggGrid, 256, 0, stream>>>(P, R, b3, row_start, cnt, eidx, hbuf, keys);
  head_kernel<<<GG, 256, 0, stream>>>(hbuf, keys, cw, cb, w1, bb1, w2, bb2, out);
}

// Round 7
// 482.125 us; speedup vs baseline: 1.0186x; 1.0186x over previous
//
#include <hip/hip_runtime.h>

#define NN 100000
#define EE 1600000
#define GG 1000
#define PERG 100
#define KK 30
#define HH 64

#define NB 782      // buckets of 128 nodes: 782*128 = 100096 >= NN
#define CAP 4096    // max edges/bucket (mean 2048, sigma ~45 -> huge margin)
#define CHB 4096    // edges per bucket block -> 391 bucket blocks
#define BUCKET_BLOCKS ((EE + CHB - 1) / CHB)  // 391
#define PROJ_BLOCKS ((NN + 127) / 128)        // 782

__global__ __launch_bounds__(1024) void zero_int(int* p, int n) {
  int i = blockIdx.x * 1024 + threadIdx.x;
  if (i < n) p[i] = 0;
}

// ---- bucket body: LDS histogram + per-(block,bucket) run reservation ----
__device__ __forceinline__ void bucket_body(int bid, float* smem,
                                            const int* __restrict__ src,
                                            const int* __restrict__ dst,
                                            int* __restrict__ gcur,
                                            int* __restrict__ pairs) {
  int* lhist = (int*)smem;
  int* lbase = lhist + NB;
  int* lcur = lbase + NB;
  const int t = threadIdx.x;
  const int c0 = bid * CHB;
  const int c1 = min(c0 + CHB, EE);
  for (int b = t; b < NB; b += 256) {
    lhist[b] = 0;
    lcur[b] = 0;
  }
  __syncthreads();
  for (int e = c0 + t; e < c1; e += 256) atomicAdd(&lhist[dst[e] >> 7], 1);
  __syncthreads();
  for (int b = t; b < NB; b += 256) {
    int c = lhist[b];
    lbase[b] = c ? atomicAdd(&gcur[b], c) : 0;
  }
  __syncthreads();
  for (int e = c0 + t; e < c1; e += 256) {
    int d = dst[e];
    int b = d >> 7;
    int p = atomicAdd(&lcur[b], 1);
    pairs[b * CAP + lbase[b] + p] = (src[e] << 7) | (d & 127);
  }
}

// ---- proj body: X [NN,K] @ (WL|WR) -> P, R. BM=128, 8x8 reg tile ----
template <int K>
__device__ __forceinline__ void proj_body(int bid, float* smem,
                                          const float* __restrict__ X,
                                          const float* __restrict__ WL,
                                          const float* __restrict__ WR,
                                          float* __restrict__ P,
                                          float* __restrict__ R) {
  constexpr int BM = 128, BK = 32, XSP = 40, WSP = 144;
  float* xs = smem;             // 128*40 floats
  float* ws = smem + BM * XSP;  // 32*144 floats
  const int t = threadIdx.x;
  const int row0 = bid * BM;
  const int tc = t & 15, tr = t >> 4;
  const int wcol = tc * 8 + (tc >> 2) * 4;

  float acc[8][8];
#pragma unroll
  for (int i = 0; i < 8; ++i)
#pragma unroll
    for (int j = 0; j < 8; ++j) acc[i][j] = 0.f;

  for (int k0 = 0; k0 < K; k0 += BK) {
    __syncthreads();
    for (int idx = t; idx < BM * 8; idx += 256) {
      int r = idx >> 3, c = idx & 7;
      int row = row0 + r;
      float4 v = make_float4(0.f, 0.f, 0.f, 0.f);
      if (row < NN) v = *reinterpret_cast<const float4*>(&X[(size_t)row * K + k0 + c * 4]);
      *reinterpret_cast<float4*>(&xs[r * XSP + c * 4]) = v;
    }
    for (int idx = t; idx < BK * 16; idx += 256) {
      int kr = idx >> 4, c4 = idx & 15;
      int gcl = c4 >> 1;
      int off = gcl * 8 + (gcl >> 2) * 4 + (c4 & 1) * 4;
      *reinterpret_cast<float4*>(&ws[kr * WSP + off]) =
          *reinterpret_cast<const float4*>(&WL[(k0 + kr) * 64 + c4 * 4]);
      int g2 = gcl + 8;
      int off2 = g2 * 8 + (g2 >> 2) * 4 + (c4 & 1) * 4;
      *reinterpret_cast<float4*>(&ws[kr * WSP + off2]) =
          *reinterpret_cast<const float4*>(&WR[(k0 + kr) * 64 + c4 * 4]);
    }
    __syncthreads();
    for (int kk4 = 0; kk4 < BK; kk4 += 4) {
      float4 a[8];
#pragma unroll
      for (int i = 0; i < 8; ++i)
        a[i] = *reinterpret_cast<const float4*>(&xs[(tr + 16 * i) * XSP + kk4]);
#pragma unroll
      for (int kk = 0; kk < 4; ++kk) {
        float4 b0 = *reinterpret_cast<const float4*>(&ws[(kk4 + kk) * WSP + wcol]);
        float4 b1 = *reinterpret_cast<const float4*>(&ws[(kk4 + kk) * WSP + wcol + 4]);
        float bv[8] = {b0.x, b0.y, b0.z, b0.w, b1.x, b1.y, b1.z, b1.w};
#pragma unroll
        for (int i = 0; i < 8; ++i) {
          float av = (kk == 0) ? a[i].x : (kk == 1) ? a[i].y : (kk == 2) ? a[i].z : a[i].w;
#pragma unroll
          for (int j = 0; j < 8; ++j) acc[i][j] = fmaf(av, bv[j], acc[i][j]);
        }
      }
    }
  }

  float* OUT = (tc < 8) ? P : R;
  int cb = (tc & 7) * 8;
#pragma unroll
  for (int i = 0; i < 8; ++i) {
    int row = row0 + tr + 16 * i;
    if (row < NN) {
      *reinterpret_cast<float4*>(&OUT[(size_t)row * 64 + cb]) =
          make_float4(acc[i][0], acc[i][1], acc[i][2], acc[i][3]);
      *reinterpret_cast<float4*>(&OUT[(size_t)row * 64 + cb + 4]) =
          make_float4(acc[i][4], acc[i][5], acc[i][6], acc[i][7]);
    }
  }
}

// Heterogeneous launch: bucket blocks (CSR phase B) co-resident with proj1
// blocks -> bucket's serial ~20us disappears into proj's barrier stalls.
__global__ __launch_bounds__(256) void fused_bucket_proj(const int* __restrict__ src,
                                                         const int* __restrict__ dst,
                                                         int* __restrict__ gcur,
                                                         int* __restrict__ pairs,
                                                         const float* __restrict__ X,
                                                         const float* __restrict__ WL,
                                                         const float* __restrict__ WR,
                                                         float* __restrict__ P,
                                                         float* __restrict__ R) {
  __shared__ float smem[128 * 40 + 32 * 144];  // 38912 B, covers both roles
  if (blockIdx.x < BUCKET_BLOCKS)
    bucket_body(blockIdx.x, smem, src, dst, gcur, pairs);
  else
    proj_body<128>(blockIdx.x - BUCKET_BLOCKS, smem, X, WL, WR, P, R);
}

template <int K>
__global__ __launch_bounds__(256) void proj_kernel(const float* __restrict__ X,
                                                   const float* __restrict__ WL,
                                                   const float* __restrict__ WR,
                                                   float* __restrict__ P,
                                                   float* __restrict__ R) {
  __shared__ float smem[128 * 40 + 32 * 144];
  proj_body<K>(blockIdx.x, smem, X, WL, WR, P, R);
}

// Phase C with inline scan: block b computes base = sum(gcur[0..b)) itself
// (<=782 L2-cached ints), then 128-bin LDS counting sort -> row_start/cnt/eidx.
__global__ __launch_bounds__(256) void csr_kernel(const int* __restrict__ gcur,
                                                  const int* __restrict__ pairs,
                                                  int* __restrict__ row_start,
                                                  int* __restrict__ cnt,
                                                  int* __restrict__ eidx) {
  __shared__ int vals[CAP];
  __shared__ int hist[128];
  __shared__ int offs[128];
  __shared__ int cur[128];
  __shared__ int red[4];
  const int b = blockIdx.x;
  const int t = threadIdx.x;
  // inline exclusive prefix over bucket counts
  int s = 0;
  for (int i = t; i < b; i += 256) s += gcur[i];
#pragma unroll
  for (int off = 32; off > 0; off >>= 1) s += __shfl_xor(s, off);
  if ((t & 63) == 0) red[t >> 6] = s;
  if (t < 128) {
    hist[t] = 0;
    cur[t] = 0;
  }
  __syncthreads();
  const int base = red[0] + red[1] + red[2] + red[3];
  const int nb = gcur[b];
  for (int i = t; i < nb; i += 256) {
    int v = pairs[b * CAP + i];
    vals[i] = v;
    atomicAdd(&hist[v & 127], 1);
  }
  __syncthreads();
  if (t < 128) {
    int ss = 0;
    for (int m = 0; m < t; ++m) ss += hist[m];
    offs[t] = ss;
    int node = b * 128 + t;
    if (node < NN) {
      row_start[node] = base + ss;
      cnt[node] = hist[t];
    }
  }
  __syncthreads();
  for (int i = t; i < nb; i += 256) {
    int v = vals[i];
    int ld = v & 127;
    int p = atomicAdd(&cur[ld], 1);
    eidx[base + offs[ld] + p] = v >> 7;
  }
}

// one wave per node, quarter-wave per edge: one dwordx4 covers 4 edges,
// 16 edges in flight.
__global__ __launch_bounds__(256) void agg_kernel(const float* __restrict__ P,
                                                  const float* __restrict__ R,
                                                  const float* __restrict__ bias,
                                                  const int* __restrict__ row_start,
                                                  const int* __restrict__ cnt,
                                                  const int* __restrict__ eidx,
                                                  float* __restrict__ h,
                                                  float* __restrict__ keys) {
  int wid = (blockIdx.x * 256 + threadIdx.x) >> 6;
  int lane = threadIdx.x & 63;
  if (wid >= NN) return;
  const int q = lane >> 4;
  const int ql = lane & 15;
  const int base = row_start[wid];
  const int deg = cnt[wid];
  float4 a0 = make_float4(0.f, 0.f, 0.f, 0.f);
  float4 a1 = make_float4(0.f, 0.f, 0.f, 0.f);

  for (int e0 = 0; e0 < deg; e0 += 64) {
    const int m = min(64, deg - e0);
    int idx = (lane < m) ? eidx[base + e0 + lane] : 0;
    for (int j = 0; j < m; j += 16) {
      const int eA = j + q, eB = j + 4 + q, eC = j + 8 + q, eD = j + 12 + q;
      const int sA = __shfl(idx, min(eA, m - 1));
      const int sB = __shfl(idx, min(eB, m - 1));
      const int sC = __shfl(idx, min(eC, m - 1));
      const int sD = __shfl(idx, min(eD, m - 1));
      const float wA = (eA < m) ? 1.f : 0.f;
      const float wB = (eB < m) ? 1.f : 0.f;
      const float wC = (eC < m) ? 1.f : 0.f;
      const float wD = (eD < m) ? 1.f : 0.f;
      float4 vA = *reinterpret_cast<const float4*>(&P[(size_t)sA * 64 + ql * 4]);
      float4 vB = *reinterpret_cast<const float4*>(&P[(size_t)sB * 64 + ql * 4]);
      float4 vC = *reinterpret_cast<const float4*>(&P[(size_t)sC * 64 + ql * 4]);
      float4 vD = *reinterpret_cast<const float4*>(&P[(size_t)sD * 64 + ql * 4]);
      a0.x = fmaf(wA, vA.x, a0.x); a0.y = fmaf(wA, vA.y, a0.y);
      a0.z = fmaf(wA, vA.z, a0.z); a0.w = fmaf(wA, vA.w, a0.w);
      a1.x = fmaf(wB, vB.x, a1.x); a1.y = fmaf(wB, vB.y, a1.y);
      a1.z = fmaf(wB, vB.z, a1.z); a1.w = fmaf(wB, vB.w, a1.w);
      a0.x = fmaf(wC, vC.x, a0.x); a0.y = fmaf(wC, vC.y, a0.y);
      a0.z = fmaf(wC, vC.z, a0.z); a0.w = fmaf(wC, vC.w, a0.w);
      a1.x = fmaf(wD, vD.x, a1.x); a1.y = fmaf(wD, vD.y, a1.y);
      a1.z = fmaf(wD, vD.z, a1.z); a1.w = fmaf(wD, vD.w, a1.w);
    }
  }

  float4 acc = make_float4(a0.x + a1.x, a0.y + a1.y, a0.z + a1.z, a0.w + a1.w);
#pragma unroll
  for (int d = 16; d < 64; d <<= 1) {
    acc.x += __shfl_xor(acc.x, d);
    acc.y += __shfl_xor(acc.y, d);
    acc.z += __shfl_xor(acc.z, d);
    acc.w += __shfl_xor(acc.w, d);
  }

  if (q == 0) {
    const float dv = fmaxf((float)deg, 1.0f);
    float4 r4 = *reinterpret_cast<const float4*>(&R[(size_t)wid * 64 + ql * 4]);
    float4 b4 = *reinterpret_cast<const float4*>(&bias[ql * 4]);
    float4 o;
    o.x = fmaxf(acc.x / dv + b4.x + r4.x, 0.f);
    o.y = fmaxf(acc.y / dv + b4.y + r4.y, 0.f);
    o.z = fmaxf(acc.z / dv + b4.z + r4.z, 0.f);
    o.w = fmaxf(acc.w / dv + b4.w + r4.w, 0.f);
    *reinterpret_cast<float4*>(&h[(size_t)wid * 64 + ql * 4]) = o;
    if (keys != nullptr && ql == 15) keys[wid] = o.w;  // feature 63
  }
}

// one block (256 thr) per graph: stable top-30, conv1d, MLP head.
__global__ __launch_bounds__(256) void head_kernel(const float* __restrict__ h,
                                                   const float* __restrict__ keysArr,
                                                   const float* __restrict__ cw,
                                                   const float* __restrict__ cb,
                                                   const float* __restrict__ w1,
                                                   const float* __restrict__ bb1,
                                                   const float* __restrict__ w2,
                                                   const float* __restrict__ bb2,
                                                   float* __restrict__ out) {
  __shared__ float key[PERG];
  __shared__ int sel[KK];
  __shared__ float feat[34 * 65];
  __shared__ float cwT[192 * 33];
  __shared__ float z[896];
  __shared__ float psum[256];
  const int g = blockIdx.x;
  const int t = threadIdx.x;

  for (int idx = t; idx < 32 * 192; idx += 256) {
    int o = idx / 192, k = idx % 192;
    cwT[k * 33 + o] = cw[idx];
  }
  if (t < PERG) key[t] = keysArr[g * PERG + t];
  __syncthreads();

  if (t < PERG) {
    float kv = key[t];
    int r = 0;
    for (int m = 0; m < PERG; ++m) {
      float km = key[m];
      r += (int)((km > kv) || (km == kv && m < t));
    }
    if (r < KK) sel[r] = t;
  }
  __syncthreads();

  for (int idx = t; idx < KK * HH; idx += 256) {
    int r = idx >> 6, f = idx & 63;
    feat[r * 65 + f] = h[(size_t)(g * PERG + sel[r]) * HH + f];
  }
  __syncthreads();

  {
    const int o = t & 31;
    const int pg = t >> 5;
    float zacc[4] = {0.f, 0.f, 0.f, 0.f};
    int i = 0, tt = 0;
    for (int k = 0; k < 192; ++k) {
      float c = cwT[k * 33 + o];
#pragma unroll
      for (int j = 0; j < 4; ++j) {
        int p = pg + 8 * j;
        zacc[j] = fmaf(c, feat[(p + tt) * 65 + i], zacc[j]);
      }
      if (++tt == 3) {
        tt = 0;
        ++i;
      }
    }
    float cbo = cb[o];
#pragma unroll
    for (int j = 0; j < 4; ++j) {
      int p = pg + 8 * j;
      if (p < 28) z[o * 28 + p] = fmaxf(zacc[j] + cbo, 0.f);
    }
  }
  __syncthreads();

  {
    const int hh = t & 63;
    const int quarter = t >> 6;
    const int q0 = quarter * 224;
    float acc = 0.f;
    for (int q = 0; q < 224; ++q)
      acc = fmaf(z[q0 + q], w1[(size_t)(q0 + q) * 64 + hh], acc);
    psum[t] = acc;
  }
  __syncthreads();

  if (t < 64) {
    float o1 = fmaxf(bb1[t] + psum[t] + psum[t + 64] + psum[t + 128] + psum[t + 192], 0.f);
    float v = o1 * w2[t];
#pragma unroll
    for (int off = 32; off > 0; off >>= 1) v += __shfl_down(v, off);
    if (t == 0) out[g] = v + bb2[0];
  }
}

extern "C" void kernel_launch(void* const* d_in, const int* in_sizes, int n_in,
                              void* d_out, int out_size, void* d_ws, size_t ws_size,
                              hipStream_t stream) {
  const float* x = (const float*)d_in[0];
  const int* src = (const int*)d_in[1];
  const int* dst = (const int*)d_in[2];
  const float* wl1 = (const float*)d_in[4];
  const float* wr1 = (const float*)d_in[5];
  const float* b1 = (const float*)d_in[6];
  const float* wl2 = (const float*)d_in[7];
  const float* wr2 = (const float*)d_in[8];
  const float* b2 = (const float*)d_in[9];
  const float* wl3 = (const float*)d_in[10];
  const float* wr3 = (const float*)d_in[11];
  const float* b3 = (const float*)d_in[12];
  const float* cw = (const float*)d_in[13];
  const float* cb = (const float*)d_in[14];
  const float* w1 = (const float*)d_in[15];
  const float* bb1 = (const float*)d_in[16];
  const float* w2 = (const float*)d_in[17];
  const float* bb2 = (const float*)d_in[18];
  float* out = (float*)d_out;

  char* w = (char*)d_ws;
  auto carve = [&](size_t bytes) {
    char* p = w;
    w += (bytes + 255) & ~(size_t)255;
    return p;
  };
  int* row_start = (int*)carve((size_t)NN * 4);
  int* cnt = (int*)carve((size_t)NN * 4);
  int* eidx = (int*)carve((size_t)EE * 4);
  float* P = (float*)carve((size_t)NN * 64 * 4);
  float* R = (float*)carve((size_t)NN * 64 * 4);
  float* hbuf = (float*)carve((size_t)NN * 64 * 4);
  float* keys = (float*)carve((size_t)NN * 4);
  int* gcur = (int*)carve((size_t)NB * 4);
  // pairs aliases hbuf (NOT P: proj1 writes P concurrently with bucket now).
  // csr reads pairs before agg1 writes hbuf (stream order) -> safe.
  int* pairs = (int*)hbuf;  // NB*CAP*4 = 12.8 MB < 25.6 MB

  zero_int<<<1, 1024, 0, stream>>>(gcur, NB);
  fused_bucket_proj<<<BUCKET_BLOCKS + PROJ_BLOCKS, 256, 0, stream>>>(
      src, dst, gcur, pairs, x, wl1, wr1, P, R);
  csr_kernel<<<NB, 256, 0, stream>>>(gcur, pairs, row_start, cnt, eidx);

  const int aggGrid = (NN + 3) / 4;
  agg_kernel<<<aggGrid, 256, 0, stream>>>(P, R, b1, row_start, cnt, eidx, hbuf, nullptr);
  proj_kernel<64><<<PROJ_BLOCKS, 256, 0, stream>>>(hbuf, wl2, wr2, P, R);
  agg_kernel<<<aggGrid, 256, 0, stream>>>(P, R, b2, row_start, cnt, eidx, hbuf, nullptr);
  proj_kernel<64><<<PROJ_BLOCKS, 256, 0, stream>>>(hbuf, wl3, wr3, P, R);
  agg_kernel<<<aggGrid, 256, 0, stream>>>(P, R, b3, row_start, cnt, eidx, hbuf, keys);
  head_kernel<<<GG, 256, 0, stream>>>(hbuf, keys, cw, cb, w1, bb1, w2, bb2, out);
}